// Round 7
// baseline (1010.694 us; speedup 1.0000x reference)
//
#include <hip/hip_runtime.h>
#include <hip/hip_fp16.h>

// SparseConvTransposeBlock, round 7: operand-swapped MFMA (compute C^T) ->
// channel-adjacent output in registers -> direct fp16 packed atomics. No LDS
// scratch, no repack, no shuffles; occupancy 6->8 blocks/CU.
//
// Established model (R1/R3/R6): k1 time = random-access bytes / ~1.8 TB/s.
// R6: FETCH 108MB (bf16 gather ~= per-XCD compulsory), WRITE 270MB (fp16
// atomic write-through), k1 220us. This round tests whether the 1.8 TB/s
// drain is concurrency-limited (R6 ran at 50% occ) and trims the ~147us of
// small-kernel overhead (fused memset, vectorized stats/normalize).
//
// A/B fragment layouts of mfma_16x16x32_bf16 are index-symmetric, so
// mfma(wfrag, feat_frag, acc) yields D[m=ch-in-tile][n=row-slot]: lane
// (quad,col) holds ch = 16*nt + 4*quad + r for output row base+col -- 4
// consecutive channels per acc tile -> 2 half2 atomics, row index already
// resident per-lane.
//
// Bias cancels in training-mode BN: y = (acc - mean_acc)*rsqrt(var)*g + b.

#define C_DIM 64
#define LDS_STRIDE 72   // bf16 elems per Wt row: 64 + 8 pad

typedef __bf16 bf16_t;
typedef bf16_t bf16x4 __attribute__((ext_vector_type(4)));
typedef bf16_t bf16x8 __attribute__((ext_vector_type(8)));
typedef float floatx4 __attribute__((ext_vector_type(4)));

// ---------------------------------------------- features f32 -> bf16 table
__global__ __launch_bounds__(256)
void k_fprep(const float* __restrict__ f, bf16_t* __restrict__ fb, int total4)
{
    int i = blockIdx.x * 256 + threadIdx.x;
    if (i < total4) {
        float4 v = ((const float4*)f)[i];
        bf16x4 o;
        o[0] = (bf16_t)v.x; o[1] = (bf16_t)v.y;
        o[2] = (bf16_t)v.z; o[3] = (bf16_t)v.w;
        ((bf16x4*)fb)[i] = o;
    }
}

// -------- main: stream pairs, operand-swapped MFMA, fp16 packed atomics
__global__ __launch_bounds__(256)
void k1_ct(const float* __restrict__ features,
           const bf16_t* __restrict__ fbf16,
           const float* __restrict__ weight,
           const int* __restrict__ pairs_in,
           const int* __restrict__ pairs_out,
           __half* __restrict__ acc,
           int P, int rows_per_block, int use_bf16)
{
    __shared__ bf16_t Wt[C_DIM * LDS_STRIDE];

    const int k   = blockIdx.y;
    const int tid = threadIdx.x;

    // Stage W_k^T into LDS as bf16: Wt[d][c] = W[k][c][d].
    const float* Wk = weight + (size_t)k * C_DIM * C_DIM;
    for (int i = tid; i < C_DIM * C_DIM; i += 256) {
        int c = i >> 6, d = i & 63;
        Wt[d * LDS_STRIDE + c] = (bf16_t)Wk[i];
    }
    __syncthreads();

    const int wave = tid >> 6;
    const int lane = tid & 63;
    const int quad = lane >> 4;
    const int col  = lane & 15;

    // Weight fragments, used as the A-operand:
    // lane holds A[m=col (ch-in-tile)][k=quad*8+j+32*ks] = W[c][ch=col+16nt].
    bf16x8 wfrag[2][4];
    #pragma unroll
    for (int ks = 0; ks < 2; ++ks)
        #pragma unroll
        for (int nt = 0; nt < 4; ++nt)
            wfrag[ks][nt] =
                *(const bf16x8*)&Wt[(col + 16 * nt) * LDS_STRIDE + quad * 8 + 32 * ks];

    const int* __restrict__ pin  = pairs_in  + (size_t)k * P;
    const int* __restrict__ pout = pairs_out + (size_t)k * P;

    const int p0   = blockIdx.x * rows_per_block;
    const int pend = min(p0 + rows_per_block, P);

    for (int base = p0 + wave * 16; base < pend; base += 64) {
        int prow    = base + col;
        int clamped = (prow < pend) ? prow : (pend - 1);
        int in_idx  = pin[clamped];
        int out_idx = pout[clamped];   // per-lane: the row this lane will write

        // Feature fragments, used as the B-operand:
        // lane holds B[k=quad*8+j+32*ks][n=col] = features[in_idx][k].
        bf16x8 a0, a1;
        if (use_bf16) {
            const bf16_t* src = fbf16 + (size_t)in_idx * C_DIM + quad * 8;
            a0 = *(const bf16x8*)(src);
            a1 = *(const bf16x8*)(src + 32);
        } else {
            const float* src = features + (size_t)in_idx * C_DIM + quad * 8;
            float4 f0 = *(const float4*)(src);
            float4 f1 = *(const float4*)(src + 4);
            float4 f2 = *(const float4*)(src + 32);
            float4 f3 = *(const float4*)(src + 36);
            a0[0] = (bf16_t)f0.x; a0[1] = (bf16_t)f0.y; a0[2] = (bf16_t)f0.z; a0[3] = (bf16_t)f0.w;
            a0[4] = (bf16_t)f1.x; a0[5] = (bf16_t)f1.y; a0[6] = (bf16_t)f1.z; a0[7] = (bf16_t)f1.w;
            a1[0] = (bf16_t)f2.x; a1[1] = (bf16_t)f2.y; a1[2] = (bf16_t)f2.z; a1[3] = (bf16_t)f2.w;
            a1[4] = (bf16_t)f3.x; a1[5] = (bf16_t)f3.y; a1[6] = (bf16_t)f3.z; a1[7] = (bf16_t)f3.w;
        }

        floatx4 ac0 = {0.f, 0.f, 0.f, 0.f};
        floatx4 ac1 = {0.f, 0.f, 0.f, 0.f};
        floatx4 ac2 = {0.f, 0.f, 0.f, 0.f};
        floatx4 ac3 = {0.f, 0.f, 0.f, 0.f};

        // D = W^T(tile nt) x feat^T : lane gets ch=16nt+4*quad+r, row-slot=col.
        ac0 = __builtin_amdgcn_mfma_f32_16x16x32_bf16(wfrag[0][0], a0, ac0, 0, 0, 0);
        ac0 = __builtin_amdgcn_mfma_f32_16x16x32_bf16(wfrag[1][0], a1, ac0, 0, 0, 0);
        ac1 = __builtin_amdgcn_mfma_f32_16x16x32_bf16(wfrag[0][1], a0, ac1, 0, 0, 0);
        ac1 = __builtin_amdgcn_mfma_f32_16x16x32_bf16(wfrag[1][1], a1, ac1, 0, 0, 0);
        ac2 = __builtin_amdgcn_mfma_f32_16x16x32_bf16(wfrag[0][2], a0, ac2, 0, 0, 0);
        ac2 = __builtin_amdgcn_mfma_f32_16x16x32_bf16(wfrag[1][2], a1, ac2, 0, 0, 0);
        ac3 = __builtin_amdgcn_mfma_f32_16x16x32_bf16(wfrag[0][3], a0, ac3, 0, 0, 0);
        ac3 = __builtin_amdgcn_mfma_f32_16x16x32_bf16(wfrag[1][3], a1, ac3, 0, 0, 0);

        if (prow < pend) {
            __half* dst = acc + (size_t)out_idx * C_DIM + 4 * quad;
            __half2 h;
            h = __floats2half2_rn(ac0[0], ac0[1]); unsafeAtomicAdd((__half2*)(dst +  0), h);
            h = __floats2half2_rn(ac0[2], ac0[3]); unsafeAtomicAdd((__half2*)(dst +  2), h);
            h = __floats2half2_rn(ac1[0], ac1[1]); unsafeAtomicAdd((__half2*)(dst + 16), h);
            h = __floats2half2_rn(ac1[2], ac1[3]); unsafeAtomicAdd((__half2*)(dst + 18), h);
            h = __floats2half2_rn(ac2[0], ac2[1]); unsafeAtomicAdd((__half2*)(dst + 32), h);
            h = __floats2half2_rn(ac2[2], ac2[3]); unsafeAtomicAdd((__half2*)(dst + 34), h);
            h = __floats2half2_rn(ac3[0], ac3[1]); unsafeAtomicAdd((__half2*)(dst + 48), h);
            h = __floats2half2_rn(ac3[2], ac3[3]); unsafeAtomicAdd((__half2*)(dst + 50), h);
        }
    }
}

// ---------------------- per-channel sum / sumsq over the fp16 accumulator
__global__ __launch_bounds__(256)
void k2_stats_h(const __half* __restrict__ acc, float* __restrict__ sums,
                int n_rows)
{
    const int tid = threadIdx.x;
    const int c8  = tid & 7;    // channel octet
    const int sub = tid >> 3;   // 32 rows per block pass

    float s[8] = {0,0,0,0,0,0,0,0}, q[8] = {0,0,0,0,0,0,0,0};
    for (int r = blockIdx.x * 32 + sub; r < n_rows; r += gridDim.x * 32) {
        float4 v = *(const float4*)&acc[(size_t)r * C_DIM + c8 * 8];
        const __half2* h = (const __half2*)&v;
        #pragma unroll
        for (int j = 0; j < 4; ++j) {
            float x = __half2float(h[j].x), y = __half2float(h[j].y);
            s[2*j]   += x; q[2*j]   += x * x;
            s[2*j+1] += y; q[2*j+1] += y * y;
        }
    }

    __shared__ float red[128];
    if (tid < 128) red[tid] = 0.f;
    __syncthreads();
    #pragma unroll
    for (int j = 0; j < 8; ++j) {
        atomicAdd(&red[c8 * 8 + j], s[j]);
        atomicAdd(&red[64 + c8 * 8 + j], q[j]);
    }
    __syncthreads();
    if (tid < 128) atomicAdd(&sums[tid], red[tid]);
}

// ------------------------- BN normalize + ReLU: fp16 acc -> fp32 out
__global__ __launch_bounds__(256)
void k3_bn_relu_h(const __half* __restrict__ acc, float* __restrict__ out,
                  const float* __restrict__ sums,
                  const float* __restrict__ gamma, const float* __restrict__ beta,
                  int n_rows)
{
    int tid = blockIdx.x * 256 + threadIdx.x;
    int c8  = tid & 7;                   // fixed channel octet per thread
    float inv_n = 1.0f / (float)n_rows;

    float sc[8], sh[8];
    #pragma unroll
    for (int j = 0; j < 8; ++j) {
        int ch    = c8 * 8 + j;
        float m   = sums[ch] * inv_n;
        float var = sums[64 + ch] * inv_n - m * m;
        float inv = rsqrtf(var + 1e-5f);
        float g   = gamma[ch] * inv;
        sc[j] = g;
        sh[j] = beta[ch] - m * g;
    }

    size_t total = (size_t)n_rows * 8;   // halfx8 octets
    for (size_t i = tid; i < total; i += (size_t)gridDim.x * 256) {
        float4 v = ((const float4*)acc)[i];
        const __half2* h = (const __half2*)&v;
        float4 o0, o1;
        o0.x = fmaxf(__half2float(h[0].x) * sc[0] + sh[0], 0.f);
        o0.y = fmaxf(__half2float(h[0].y) * sc[1] + sh[1], 0.f);
        o0.z = fmaxf(__half2float(h[1].x) * sc[2] + sh[2], 0.f);
        o0.w = fmaxf(__half2float(h[1].y) * sc[3] + sh[3], 0.f);
        o1.x = fmaxf(__half2float(h[2].x) * sc[4] + sh[4], 0.f);
        o1.y = fmaxf(__half2float(h[2].y) * sc[5] + sh[5], 0.f);
        o1.z = fmaxf(__half2float(h[3].x) * sc[6] + sh[6], 0.f);
        o1.w = fmaxf(__half2float(h[3].y) * sc[7] + sh[7], 0.f);
        ((float4*)out)[2 * i]     = o0;
        ((float4*)out)[2 * i + 1] = o1;
    }
}

// ===================== fallback (R1 path, proven) ===========================
__global__ __launch_bounds__(256)
void k1_scatter_gemm(const float* __restrict__ features,
                     const float* __restrict__ weight,
                     const int* __restrict__ pairs_in,
                     const int* __restrict__ pairs_out,
                     float* __restrict__ out,
                     int P, int rows_per_block)
{
    __shared__ bf16_t Wt[C_DIM * LDS_STRIDE];
    const int k   = blockIdx.y;
    const int tid = threadIdx.x;
    const float* Wk = weight + (size_t)k * C_DIM * C_DIM;
    for (int i = tid; i < C_DIM * C_DIM; i += 256) {
        int c = i >> 6, d = i & 63;
        Wt[d * LDS_STRIDE + c] = (bf16_t)Wk[i];
    }
    __syncthreads();
    const int wave = tid >> 6, lane = tid & 63, quad = lane >> 4, col = lane & 15;
    bf16x8 bfrag[2][4];
    #pragma unroll
    for (int ks = 0; ks < 2; ++ks)
        #pragma unroll
        for (int nt = 0; nt < 4; ++nt)
            bfrag[ks][nt] =
                *(const bf16x8*)&Wt[(col + 16 * nt) * LDS_STRIDE + quad * 8 + 32 * ks];
    const int* __restrict__ pin  = pairs_in  + (size_t)k * P;
    const int* __restrict__ pout = pairs_out + (size_t)k * P;
    const int p0   = blockIdx.x * rows_per_block;
    const int pend = min(p0 + rows_per_block, P);
    for (int base = p0 + wave * 16; base < pend; base += 64) {
        int prow    = base + col;
        int clamped = (prow < pend) ? prow : (pend - 1);
        int in_idx  = pin[clamped];
        int out_idx = pout[clamped];
        const float* src = features + (size_t)in_idx * C_DIM + quad * 8;
        float4 f0 = *(const float4*)(src);
        float4 f1 = *(const float4*)(src + 4);
        float4 f2 = *(const float4*)(src + 32);
        float4 f3 = *(const float4*)(src + 36);
        bf16x8 a0, a1;
        a0[0] = (bf16_t)f0.x; a0[1] = (bf16_t)f0.y; a0[2] = (bf16_t)f0.z; a0[3] = (bf16_t)f0.w;
        a0[4] = (bf16_t)f1.x; a0[5] = (bf16_t)f1.y; a0[6] = (bf16_t)f1.z; a0[7] = (bf16_t)f1.w;
        a1[0] = (bf16_t)f2.x; a1[1] = (bf16_t)f2.y; a1[2] = (bf16_t)f2.z; a1[3] = (bf16_t)f2.w;
        a1[4] = (bf16_t)f3.x; a1[5] = (bf16_t)f3.y; a1[6] = (bf16_t)f3.z; a1[7] = (bf16_t)f3.w;
        floatx4 acc0 = {0.f,0.f,0.f,0.f}, acc1 = {0.f,0.f,0.f,0.f};
        floatx4 acc2 = {0.f,0.f,0.f,0.f}, acc3 = {0.f,0.f,0.f,0.f};
        acc0 = __builtin_amdgcn_mfma_f32_16x16x32_bf16(a0, bfrag[0][0], acc0, 0, 0, 0);
        acc0 = __builtin_amdgcn_mfma_f32_16x16x32_bf16(a1, bfrag[1][0], acc0, 0, 0, 0);
        acc1 = __builtin_amdgcn_mfma_f32_16x16x32_bf16(a0, bfrag[0][1], acc1, 0, 0, 0);
        acc1 = __builtin_amdgcn_mfma_f32_16x16x32_bf16(a1, bfrag[1][1], acc1, 0, 0, 0);
        acc2 = __builtin_amdgcn_mfma_f32_16x16x32_bf16(a0, bfrag[0][2], acc2, 0, 0, 0);
        acc2 = __builtin_amdgcn_mfma_f32_16x16x32_bf16(a1, bfrag[1][2], acc2, 0, 0, 0);
        acc3 = __builtin_amdgcn_mfma_f32_16x16x32_bf16(a0, bfrag[0][3], acc3, 0, 0, 0);
        acc3 = __builtin_amdgcn_mfma_f32_16x16x32_bf16(a1, bfrag[1][3], acc3, 0, 0, 0);
        #pragma unroll
        for (int r = 0; r < 4; ++r) {
            int m = quad * 4 + r;
            int g = __shfl(out_idx, m);
            if (base + m < pend) {
                float* dst = out + (size_t)g * C_DIM + col;
                unsafeAtomicAdd(dst +  0, acc0[r]);
                unsafeAtomicAdd(dst + 16, acc1[r]);
                unsafeAtomicAdd(dst + 32, acc2[r]);
                unsafeAtomicAdd(dst + 48, acc3[r]);
            }
        }
    }
}

__global__ __launch_bounds__(256)
void k2_stats(const float* __restrict__ acc, float* __restrict__ sums, int n_rows)
{
    int tid = threadIdx.x;
    int ch  = tid & 63;
    int sub = tid >> 6;
    float s = 0.f, s2 = 0.f;
    for (int r = blockIdx.x * 4 + sub; r < n_rows; r += gridDim.x * 4) {
        float v = acc[(size_t)r * C_DIM + ch];
        s  += v;
        s2 += v * v;
    }
    __shared__ float red[256];
    red[tid] = s;
    __syncthreads();
    if (tid < 64) {
        float t = red[tid] + red[tid + 64] + red[tid + 128] + red[tid + 192];
        atomicAdd(&sums[ch], t);
    }
    __syncthreads();
    red[tid] = s2;
    __syncthreads();
    if (tid < 64) {
        float t = red[tid] + red[tid + 64] + red[tid + 128] + red[tid + 192];
        atomicAdd(&sums[64 + ch], t);
    }
}

__global__ __launch_bounds__(256)
void k3_bn_relu(float* __restrict__ out, const float* __restrict__ sums,
                const float* __restrict__ gamma, const float* __restrict__ beta,
                int n_rows)
{
    int tid = blockIdx.x * 256 + threadIdx.x;
    int ch0 = (tid * 4) & 63;
    float inv_n = 1.0f / (float)n_rows;
    float sc[4], sh[4];
    #pragma unroll
    for (int j = 0; j < 4; ++j) {
        int ch    = ch0 + j;
        float m   = sums[ch] * inv_n;
        float var = sums[64 + ch] * inv_n - m * m;
        float inv = rsqrtf(var + 1e-5f);
        float g   = gamma[ch] * inv;
        sc[j] = g;
        sh[j] = beta[ch] - m * g;
    }
    size_t total = (size_t)n_rows * C_DIM / 4;
    for (size_t i = tid; i < total; i += (size_t)gridDim.x * 256) {
        float4 v = ((const float4*)out)[i];
        v.x = fmaxf(v.x * sc[0] + sh[0], 0.f);
        v.y = fmaxf(v.y * sc[1] + sh[1], 0.f);
        v.z = fmaxf(v.z * sc[2] + sh[2], 0.f);
        v.w = fmaxf(v.w * sc[3] + sh[3], 0.f);
        ((float4*)out)[i] = v;
    }
}

// ============================================================================
extern "C" void kernel_launch(void* const* d_in, const int* in_sizes, int n_in,
                              void* d_out, int out_size, void* d_ws, size_t ws_size,
                              hipStream_t stream)
{
    const float* features  = (const float*)d_in[0];
    const float* weight    = (const float*)d_in[1];
    // d_in[2] = bias (cancels in training-mode BN)
    const float* gamma     = (const float*)d_in[3];
    const float* beta      = (const float*)d_in[4];
    const int*   pairs_in  = (const int*)d_in[5];
    const int*   pairs_out = (const int*)d_in[6];

    const int n_out     = out_size / C_DIM;
    const int n_in_rows = in_sizes[0] / C_DIM;
    const int K3        = in_sizes[1] / (C_DIM * C_DIM);
    const int P         = in_sizes[5] / K3;

    float* out = (float*)d_out;

    // ws layout: sums(512B) | fp16 acc | bf16 features
    size_t acc_bytes = (size_t)n_out * C_DIM * 2;
    size_t off_acc   = 512;
    size_t off_fb    = (off_acc + acc_bytes + 255) & ~(size_t)255;
    size_t fb_bytes  = (size_t)n_in_rows * C_DIM * 2;
    size_t need_b    = off_acc + acc_bytes;
    size_t need_a    = off_fb + fb_bytes;

    float*  sums  = (float*)d_ws;
    __half* acc   = (__half*)((char*)d_ws + off_acc);
    bf16_t* fbf16 = (bf16_t*)((char*)d_ws + off_fb);

    const int rows_per_block = 512;
    dim3 g1((P + rows_per_block - 1) / rows_per_block, K3);

    if (ws_size >= need_b) {
        const int use_bf16 = (ws_size >= need_a) ? 1 : 0;

        // single fused clear: sums (512B) + fp16 accumulator
        hipMemsetAsync(d_ws, 0, off_acc + acc_bytes, stream);
        if (use_bf16)
            k_fprep<<<(n_in_rows * 16 + 255) / 256, 256, 0, stream>>>(
                features, fbf16, n_in_rows * 16);

        k1_ct<<<g1, 256, 0, stream>>>(features, fbf16, weight, pairs_in,
                                      pairs_out, acc, P, rows_per_block,
                                      use_bf16);

        k2_stats_h<<<dim3(256), 256, 0, stream>>>(acc, sums, n_out);
        k3_bn_relu_h<<<dim3(512), 256, 0, stream>>>(acc, out, sums, gamma,
                                                    beta, n_out);
    } else {
        // fallback: proven R1 path
        hipMemsetAsync(d_out, 0, (size_t)out_size * sizeof(float), stream);
        hipMemsetAsync(d_ws, 0, 512, stream);

        k1_scatter_gemm<<<g1, 256, 0, stream>>>(features, weight, pairs_in,
                                                pairs_out, out, P, rows_per_block);
        k2_stats<<<dim3(1024), 256, 0, stream>>>(out, sums, n_out);
        k3_bn_relu<<<dim3(1024), 256, 0, stream>>>(out, sums, gamma, beta, n_out);
    }
}

// Round 8
// 352.820 us; speedup vs baseline: 2.8646x; 2.8646x over previous
//
#include <hip/hip_runtime.h>
#include <hip/hip_fp16.h>

// SparseConvTransposeBlock, round 8: R6's k1 (proven optimal) + R7's epilogue.
//
// Final drain model, fit on R1/R3/R6/R7:
//   t_k1 = max(random_bytes / 1.8 TB/s, requests / 19.6 G/s)
// R6's k1 is byte-bound at the floor: fp16 payload 128 B/row (270MB, full
// 32B sectors via wave-contiguous pk-atomics) + 108MB compulsory bf16
// gather (12.8MB table x 8 XCDs). R7's per-lane scattered half2 atomics
// broke sector packing (540MB) AND hit the 19.6 G req/s cap -> reverted.
//
// Bias cancels in training-mode BN: y = (acc - mean_acc)*rsqrt(var)*g + b.

#define C_DIM 64
#define LDS_STRIDE 72   // bf16 elems per Wt row: 64 + 8 pad
#define ROW_STRIDE 68   // fp32 elems per scratch row: 64 + 4 pad

typedef __bf16 bf16_t;
typedef bf16_t bf16x4 __attribute__((ext_vector_type(4)));
typedef bf16_t bf16x8 __attribute__((ext_vector_type(8)));
typedef float floatx4 __attribute__((ext_vector_type(4)));

// ---------------------------------------------- features f32 -> bf16 table
__global__ __launch_bounds__(256)
void k_fprep(const float* __restrict__ f, bf16_t* __restrict__ fb, int total4)
{
    int i = blockIdx.x * 256 + threadIdx.x;
    if (i < total4) {
        float4 v = ((const float4*)f)[i];
        bf16x4 o;
        o[0] = (bf16_t)v.x; o[1] = (bf16_t)v.y;
        o[2] = (bf16_t)v.z; o[3] = (bf16_t)v.w;
        ((bf16x4*)fb)[i] = o;
    }
}

// ------------------- main: stream pairs, MFMA, fp16 packed atomic scatter
// (R6 kernel, measured 220us: byte-bound at the atomic write-through floor)
__global__ __launch_bounds__(256)
void k1_fp16(const float* __restrict__ features,
             const bf16_t* __restrict__ fbf16,
             const float* __restrict__ weight,
             const int* __restrict__ pairs_in,
             const int* __restrict__ pairs_out,
             __half* __restrict__ acc,
             int P, int rows_per_block, int use_bf16)
{
    __shared__ bf16_t Wt[C_DIM * LDS_STRIDE];
    __shared__ float  scratch[4][16 * ROW_STRIDE];

    const int k   = blockIdx.y;
    const int tid = threadIdx.x;

    // Stage W_k^T into LDS as bf16: Wt[d][c] = W[k][c][d].
    const float* Wk = weight + (size_t)k * C_DIM * C_DIM;
    for (int i = tid; i < C_DIM * C_DIM; i += 256) {
        int c = i >> 6, d = i & 63;
        Wt[d * LDS_STRIDE + c] = (bf16_t)Wk[i];
    }
    __syncthreads();

    const int wave = tid >> 6;
    const int lane = tid & 63;
    const int quad = lane >> 4;
    const int col  = lane & 15;
    const int sub  = lane >> 5;   // 0/1: which of 2 rows in the pk-atomic loop
    const int c2   = lane & 31;   // half2 column index
    float* ls = &scratch[wave][0];

    // B fragments: lane holds B[kk = quad*8+j+32*ks][n = col+16*nt] = Wt[n][kk].
    bf16x8 bfrag[2][4];
    #pragma unroll
    for (int ks = 0; ks < 2; ++ks)
        #pragma unroll
        for (int nt = 0; nt < 4; ++nt)
            bfrag[ks][nt] =
                *(const bf16x8*)&Wt[(col + 16 * nt) * LDS_STRIDE + quad * 8 + 32 * ks];

    const int* __restrict__ pin  = pairs_in  + (size_t)k * P;
    const int* __restrict__ pout = pairs_out + (size_t)k * P;

    const int p0   = blockIdx.x * rows_per_block;
    const int pend = min(p0 + rows_per_block, P);

    for (int base = p0 + wave * 16; base < pend; base += 64) {
        int prow    = base + col;
        int clamped = (prow < pend) ? prow : (pend - 1);
        int in_idx  = pin[clamped];
        int out_idx = pout[clamped];   // lanes 0..15 hold rows base..base+15

        // Gather A fragments in MFMA A-layout:
        // A[m = col][kk = quad*8 + j + 32*ks] = features[in_idx][kk].
        bf16x8 a0, a1;
        if (use_bf16) {
            const bf16_t* src = fbf16 + (size_t)in_idx * C_DIM + quad * 8;
            a0 = *(const bf16x8*)(src);
            a1 = *(const bf16x8*)(src + 32);
        } else {
            const float* src = features + (size_t)in_idx * C_DIM + quad * 8;
            float4 f0 = *(const float4*)(src);
            float4 f1 = *(const float4*)(src + 4);
            float4 f2 = *(const float4*)(src + 32);
            float4 f3 = *(const float4*)(src + 36);
            a0[0] = (bf16_t)f0.x; a0[1] = (bf16_t)f0.y; a0[2] = (bf16_t)f0.z; a0[3] = (bf16_t)f0.w;
            a0[4] = (bf16_t)f1.x; a0[5] = (bf16_t)f1.y; a0[6] = (bf16_t)f1.z; a0[7] = (bf16_t)f1.w;
            a1[0] = (bf16_t)f2.x; a1[1] = (bf16_t)f2.y; a1[2] = (bf16_t)f2.z; a1[3] = (bf16_t)f2.w;
            a1[4] = (bf16_t)f3.x; a1[5] = (bf16_t)f3.y; a1[6] = (bf16_t)f3.z; a1[7] = (bf16_t)f3.w;
        }

        floatx4 acc0 = {0.f, 0.f, 0.f, 0.f};
        floatx4 acc1 = {0.f, 0.f, 0.f, 0.f};
        floatx4 acc2 = {0.f, 0.f, 0.f, 0.f};
        floatx4 acc3 = {0.f, 0.f, 0.f, 0.f};

        acc0 = __builtin_amdgcn_mfma_f32_16x16x32_bf16(a0, bfrag[0][0], acc0, 0, 0, 0);
        acc0 = __builtin_amdgcn_mfma_f32_16x16x32_bf16(a1, bfrag[1][0], acc0, 0, 0, 0);
        acc1 = __builtin_amdgcn_mfma_f32_16x16x32_bf16(a0, bfrag[0][1], acc1, 0, 0, 0);
        acc1 = __builtin_amdgcn_mfma_f32_16x16x32_bf16(a1, bfrag[1][1], acc1, 0, 0, 0);
        acc2 = __builtin_amdgcn_mfma_f32_16x16x32_bf16(a0, bfrag[0][2], acc2, 0, 0, 0);
        acc2 = __builtin_amdgcn_mfma_f32_16x16x32_bf16(a1, bfrag[1][2], acc2, 0, 0, 0);
        acc3 = __builtin_amdgcn_mfma_f32_16x16x32_bf16(a0, bfrag[0][3], acc3, 0, 0, 0);
        acc3 = __builtin_amdgcn_mfma_f32_16x16x32_bf16(a1, bfrag[1][3], acc3, 0, 0, 0);

        // Repack C tile into per-wave LDS: ls[m][ch], m = quad*4+r, ch = col+16j.
        #pragma unroll
        for (int r = 0; r < 4; ++r) {
            int m = quad * 4 + r;
            ls[m * ROW_STRIDE + col +  0] = acc0[r];
            ls[m * ROW_STRIDE + col + 16] = acc1[r];
            ls[m * ROW_STRIDE + col + 32] = acc2[r];
            ls[m * ROW_STRIDE + col + 48] = acc3[r];
        }
        // Wave-private scratch: drain LDS only (keep global atomics in flight).
        asm volatile("s_waitcnt lgkmcnt(0)" ::: "memory");

        // fp16 packed atomics: 2 rows per instruction, 32 half2 per row.
        // Per row: 128B contiguous = 4 full 32B sectors (sector-packed).
        #pragma unroll
        for (int m2 = 0; m2 < 8; ++m2) {
            int m = m2 * 2 + sub;
            float2 v = *(const float2*)&ls[m * ROW_STRIDE + 2 * c2];
            __half2 h = __floats2half2_rn(v.x, v.y);
            int g = __shfl(out_idx, m);
            if (base + m < pend)
                unsafeAtomicAdd((__half2*)(acc + (size_t)g * C_DIM + 2 * c2), h);
        }
    }
}

// ---------------------- per-channel sum / sumsq over the fp16 accumulator
__global__ __launch_bounds__(256)
void k2_stats_h(const __half* __restrict__ acc, float* __restrict__ sums,
                int n_rows)
{
    const int tid = threadIdx.x;
    const int c8  = tid & 7;    // channel octet
    const int sub = tid >> 3;   // 32 rows per block pass

    float s[8] = {0,0,0,0,0,0,0,0}, q[8] = {0,0,0,0,0,0,0,0};
    for (int r = blockIdx.x * 32 + sub; r < n_rows; r += gridDim.x * 32) {
        float4 v = *(const float4*)&acc[(size_t)r * C_DIM + c8 * 8];
        const __half2* h = (const __half2*)&v;
        #pragma unroll
        for (int j = 0; j < 4; ++j) {
            float x = __half2float(h[j].x), y = __half2float(h[j].y);
            s[2*j]   += x; q[2*j]   += x * x;
            s[2*j+1] += y; q[2*j+1] += y * y;
        }
    }

    __shared__ float red[128];
    if (tid < 128) red[tid] = 0.f;
    __syncthreads();
    #pragma unroll
    for (int j = 0; j < 8; ++j) {
        atomicAdd(&red[c8 * 8 + j], s[j]);
        atomicAdd(&red[64 + c8 * 8 + j], q[j]);
    }
    __syncthreads();
    if (tid < 128) atomicAdd(&sums[tid], red[tid]);
}

// ------------------------- BN normalize + ReLU: fp16 acc -> fp32 out
__global__ __launch_bounds__(256)
void k3_bn_relu_h(const __half* __restrict__ acc, float* __restrict__ out,
                  const float* __restrict__ sums,
                  const float* __restrict__ gamma, const float* __restrict__ beta,
                  int n_rows)
{
    int tid = blockIdx.x * 256 + threadIdx.x;
    int c8  = tid & 7;                   // fixed channel octet per thread
    float inv_n = 1.0f / (float)n_rows;

    float sc[8], sh[8];
    #pragma unroll
    for (int j = 0; j < 8; ++j) {
        int ch    = c8 * 8 + j;
        float m   = sums[ch] * inv_n;
        float var = sums[64 + ch] * inv_n - m * m;
        float inv = rsqrtf(var + 1e-5f);
        float g   = gamma[ch] * inv;
        sc[j] = g;
        sh[j] = beta[ch] - m * g;
    }

    size_t total = (size_t)n_rows * 8;   // halfx8 octets
    for (size_t i = tid; i < total; i += (size_t)gridDim.x * 256) {
        float4 v = ((const float4*)acc)[i];
        const __half2* h = (const __half2*)&v;
        float4 o0, o1;
        o0.x = fmaxf(__half2float(h[0].x) * sc[0] + sh[0], 0.f);
        o0.y = fmaxf(__half2float(h[0].y) * sc[1] + sh[1], 0.f);
        o0.z = fmaxf(__half2float(h[1].x) * sc[2] + sh[2], 0.f);
        o0.w = fmaxf(__half2float(h[1].y) * sc[3] + sh[3], 0.f);
        o1.x = fmaxf(__half2float(h[2].x) * sc[4] + sh[4], 0.f);
        o1.y = fmaxf(__half2float(h[2].y) * sc[5] + sh[5], 0.f);
        o1.z = fmaxf(__half2float(h[3].x) * sc[6] + sh[6], 0.f);
        o1.w = fmaxf(__half2float(h[3].y) * sc[7] + sh[7], 0.f);
        ((float4*)out)[2 * i]     = o0;
        ((float4*)out)[2 * i + 1] = o1;
    }
}

// ===================== fallback (R1 path, proven) ===========================
__global__ __launch_bounds__(256)
void k1_scatter_gemm(const float* __restrict__ features,
                     const float* __restrict__ weight,
                     const int* __restrict__ pairs_in,
                     const int* __restrict__ pairs_out,
                     float* __restrict__ out,
                     int P, int rows_per_block)
{
    __shared__ bf16_t Wt[C_DIM * LDS_STRIDE];
    const int k   = blockIdx.y;
    const int tid = threadIdx.x;
    const float* Wk = weight + (size_t)k * C_DIM * C_DIM;
    for (int i = tid; i < C_DIM * C_DIM; i += 256) {
        int c = i >> 6, d = i & 63;
        Wt[d * LDS_STRIDE + c] = (bf16_t)Wk[i];
    }
    __syncthreads();
    const int wave = tid >> 6, lane = tid & 63, quad = lane >> 4, col = lane & 15;
    bf16x8 bfrag[2][4];
    #pragma unroll
    for (int ks = 0; ks < 2; ++ks)
        #pragma unroll
        for (int nt = 0; nt < 4; ++nt)
            bfrag[ks][nt] =
                *(const bf16x8*)&Wt[(col + 16 * nt) * LDS_STRIDE + quad * 8 + 32 * ks];
    const int* __restrict__ pin  = pairs_in  + (size_t)k * P;
    const int* __restrict__ pout = pairs_out + (size_t)k * P;
    const int p0   = blockIdx.x * rows_per_block;
    const int pend = min(p0 + rows_per_block, P);
    for (int base = p0 + wave * 16; base < pend; base += 64) {
        int prow    = base + col;
        int clamped = (prow < pend) ? prow : (pend - 1);
        int in_idx  = pin[clamped];
        int out_idx = pout[clamped];
        const float* src = features + (size_t)in_idx * C_DIM + quad * 8;
        float4 f0 = *(const float4*)(src);
        float4 f1 = *(const float4*)(src + 4);
        float4 f2 = *(const float4*)(src + 32);
        float4 f3 = *(const float4*)(src + 36);
        bf16x8 a0, a1;
        a0[0] = (bf16_t)f0.x; a0[1] = (bf16_t)f0.y; a0[2] = (bf16_t)f0.z; a0[3] = (bf16_t)f0.w;
        a0[4] = (bf16_t)f1.x; a0[5] = (bf16_t)f1.y; a0[6] = (bf16_t)f1.z; a0[7] = (bf16_t)f1.w;
        a1[0] = (bf16_t)f2.x; a1[1] = (bf16_t)f2.y; a1[2] = (bf16_t)f2.z; a1[3] = (bf16_t)f2.w;
        a1[4] = (bf16_t)f3.x; a1[5] = (bf16_t)f3.y; a1[6] = (bf16_t)f3.z; a1[7] = (bf16_t)f3.w;
        floatx4 acc0 = {0.f,0.f,0.f,0.f}, acc1 = {0.f,0.f,0.f,0.f};
        floatx4 acc2 = {0.f,0.f,0.f,0.f}, acc3 = {0.f,0.f,0.f,0.f};
        acc0 = __builtin_amdgcn_mfma_f32_16x16x32_bf16(a0, bfrag[0][0], acc0, 0, 0, 0);
        acc0 = __builtin_amdgcn_mfma_f32_16x16x32_bf16(a1, bfrag[1][0], acc0, 0, 0, 0);
        acc1 = __builtin_amdgcn_mfma_f32_16x16x32_bf16(a0, bfrag[0][1], acc1, 0, 0, 0);
        acc1 = __builtin_amdgcn_mfma_f32_16x16x32_bf16(a1, bfrag[1][1], acc1, 0, 0, 0);
        acc2 = __builtin_amdgcn_mfma_f32_16x16x32_bf16(a0, bfrag[0][2], acc2, 0, 0, 0);
        acc2 = __builtin_amdgcn_mfma_f32_16x16x32_bf16(a1, bfrag[1][2], acc2, 0, 0, 0);
        acc3 = __builtin_amdgcn_mfma_f32_16x16x32_bf16(a0, bfrag[0][3], acc3, 0, 0, 0);
        acc3 = __builtin_amdgcn_mfma_f32_16x16x32_bf16(a1, bfrag[1][3], acc3, 0, 0, 0);
        #pragma unroll
        for (int r = 0; r < 4; ++r) {
            int m = quad * 4 + r;
            int g = __shfl(out_idx, m);
            if (base + m < pend) {
                float* dst = out + (size_t)g * C_DIM + col;
                unsafeAtomicAdd(dst +  0, acc0[r]);
                unsafeAtomicAdd(dst + 16, acc1[r]);
                unsafeAtomicAdd(dst + 32, acc2[r]);
                unsafeAtomicAdd(dst + 48, acc3[r]);
            }
        }
    }
}

__global__ __launch_bounds__(256)
void k2_stats(const float* __restrict__ acc, float* __restrict__ sums, int n_rows)
{
    int tid = threadIdx.x;
    int ch  = tid & 63;
    int sub = tid >> 6;
    float s = 0.f, s2 = 0.f;
    for (int r = blockIdx.x * 4 + sub; r < n_rows; r += gridDim.x * 4) {
        float v = acc[(size_t)r * C_DIM + ch];
        s  += v;
        s2 += v * v;
    }
    __shared__ float red[256];
    red[tid] = s;
    __syncthreads();
    if (tid < 64) {
        float t = red[tid] + red[tid + 64] + red[tid + 128] + red[tid + 192];
        atomicAdd(&sums[ch], t);
    }
    __syncthreads();
    red[tid] = s2;
    __syncthreads();
    if (tid < 64) {
        float t = red[tid] + red[tid + 64] + red[tid + 128] + red[tid + 192];
        atomicAdd(&sums[64 + ch], t);
    }
}

__global__ __launch_bounds__(256)
void k3_bn_relu(float* __restrict__ out, const float* __restrict__ sums,
                const float* __restrict__ gamma, const float* __restrict__ beta,
                int n_rows)
{
    int tid = blockIdx.x * 256 + threadIdx.x;
    int ch0 = (tid * 4) & 63;
    float inv_n = 1.0f / (float)n_rows;
    float sc[4], sh[4];
    #pragma unroll
    for (int j = 0; j < 4; ++j) {
        int ch    = ch0 + j;
        float m   = sums[ch] * inv_n;
        float var = sums[64 + ch] * inv_n - m * m;
        float inv = rsqrtf(var + 1e-5f);
        float g   = gamma[ch] * inv;
        sc[j] = g;
        sh[j] = beta[ch] - m * g;
    }
    size_t total = (size_t)n_rows * C_DIM / 4;
    for (size_t i = tid; i < total; i += (size_t)gridDim.x * 256) {
        float4 v = ((const float4*)out)[i];
        v.x = fmaxf(v.x * sc[0] + sh[0], 0.f);
        v.y = fmaxf(v.y * sc[1] + sh[1], 0.f);
        v.z = fmaxf(v.z * sc[2] + sh[2], 0.f);
        v.w = fmaxf(v.w * sc[3] + sh[3], 0.f);
        ((float4*)out)[i] = v;
    }
}

// ============================================================================
extern "C" void kernel_launch(void* const* d_in, const int* in_sizes, int n_in,
                              void* d_out, int out_size, void* d_ws, size_t ws_size,
                              hipStream_t stream)
{
    const float* features  = (const float*)d_in[0];
    const float* weight    = (const float*)d_in[1];
    // d_in[2] = bias (cancels in training-mode BN)
    const float* gamma     = (const float*)d_in[3];
    const float* beta      = (const float*)d_in[4];
    const int*   pairs_in  = (const int*)d_in[5];
    const int*   pairs_out = (const int*)d_in[6];

    const int n_out     = out_size / C_DIM;
    const int n_in_rows = in_sizes[0] / C_DIM;
    const int K3        = in_sizes[1] / (C_DIM * C_DIM);
    const int P         = in_sizes[5] / K3;

    float* out = (float*)d_out;

    // ws layout: sums(512B) | fp16 acc | bf16 features
    size_t acc_bytes = (size_t)n_out * C_DIM * 2;
    size_t off_acc   = 512;
    size_t off_fb    = (off_acc + acc_bytes + 255) & ~(size_t)255;
    size_t fb_bytes  = (size_t)n_in_rows * C_DIM * 2;
    size_t need_b    = off_acc + acc_bytes;
    size_t need_a    = off_fb + fb_bytes;

    float*  sums  = (float*)d_ws;
    __half* acc   = (__half*)((char*)d_ws + off_acc);
    bf16_t* fbf16 = (bf16_t*)((char*)d_ws + off_fb);

    const int rows_per_block = 512;
    dim3 g1((P + rows_per_block - 1) / rows_per_block, K3);

    if (ws_size >= need_b) {
        const int use_bf16 = (ws_size >= need_a) ? 1 : 0;

        // single fused clear: sums (512B) + fp16 accumulator
        hipMemsetAsync(d_ws, 0, off_acc + acc_bytes, stream);
        if (use_bf16)
            k_fprep<<<(n_in_rows * 16 + 255) / 256, 256, 0, stream>>>(
                features, fbf16, n_in_rows * 16);

        k1_fp16<<<g1, 256, 0, stream>>>(features, fbf16, weight, pairs_in,
                                        pairs_out, acc, P, rows_per_block,
                                        use_bf16);

        k2_stats_h<<<dim3(256), 256, 0, stream>>>(acc, sums, n_out);
        k3_bn_relu_h<<<dim3(512), 256, 0, stream>>>(acc, out, sums, gamma,
                                                    beta, n_out);
    } else {
        // fallback: proven R1 path
        hipMemsetAsync(d_out, 0, (size_t)out_size * sizeof(float), stream);
        hipMemsetAsync(d_ws, 0, 512, stream);

        k1_scatter_gemm<<<g1, 256, 0, stream>>>(features, weight, pairs_in,
                                                pairs_out, out, P, rows_per_block);
        k2_stats<<<dim3(1024), 256, 0, stream>>>(out, sums, n_out);
        k3_bn_relu<<<dim3(1024), 256, 0, stream>>>(out, sums, gamma, beta, n_out);
    }
}